// Round 2
// baseline (86.031 us; speedup 1.0000x reference)
//
#include <hip/hip_runtime.h>
#include <hip/hip_bf16.h>

typedef __bf16 bf16_t;
typedef __bf16 bf16x8 __attribute__((ext_vector_type(8)));
typedef float f32x4 __attribute__((ext_vector_type(4)));

#define NB 1024
#define ND 32
#define VD 64
#define NH 256
#define NK 2048

// workspace layout (bytes)
#define OFF_A    0                       // 1024*2048 bf16 = 4 MB
#define OFF_W1T  (4u*1024u*1024u)        // 32*256*2048 bf16 = 32 MB
#define OFF_W2T  (36u*1024u*1024u)       // 32*64*256 bf16 = 1 MB

#define GLD16(gsrc, ldst) \
  __builtin_amdgcn_global_load_lds((const __attribute__((address_space(1))) void*)(gsrc), \
                                   (__attribute__((address_space(3))) void*)(ldst), 16, 0, 0)

// ---------------- prep: cast A, fold adj into W1 + transpose, transpose W2 ----------------
__global__ __launch_bounds__(256) void prep_kernel(
    const float* __restrict__ cv, const float* __restrict__ adj,
    const float* __restrict__ W1, const float* __restrict__ W2,
    bf16_t* __restrict__ A, bf16_t* __restrict__ W1T, bf16_t* __restrict__ W2T)
{
  int bx = blockIdx.x;
  int tid = threadIdx.x;
  if (bx < 8192) {
    // W1effT[i][h][k] = bf16(adj[i][k/64] * W1[i][k][h]); one 16B chunk (8 k) per thread
    int t = bx * 256 + tid;          // 0..2M-1
    int i = t >> 16;                 // 65536 chunks per i
    int rem = t & 65535;
    int k8 = rem >> 8;               // 0..255 (k block of 8)
    int h = rem & 255;               // consecutive lanes -> consecutive h (coalesced reads)
    float a = adj[i * 32 + (k8 >> 3)];
    const float* src = W1 + ((size_t)(i * 2048 + k8 * 8)) * 256 + h;
    bf16x8 o;
#pragma unroll
    for (int r = 0; r < 8; ++r) o[r] = (bf16_t)(a * src[(size_t)r * 256]);
    *(bf16x8*)(W1T + ((size_t)(i * 256 + h)) * 2048 + k8 * 8) = o;
  } else if (bx < 8192 + 1024) {
    // A_bf16: straight cast, 8 elems/thread
    int t = (bx - 8192) * 256 + tid; // 0..256K-1
    const float4* s = (const float4*)cv + (size_t)t * 2;
    float4 v0 = s[0], v1 = s[1];
    bf16x8 o;
    o[0] = (bf16_t)v0.x; o[1] = (bf16_t)v0.y; o[2] = (bf16_t)v0.z; o[3] = (bf16_t)v0.w;
    o[4] = (bf16_t)v1.x; o[5] = (bf16_t)v1.y; o[6] = (bf16_t)v1.z; o[7] = (bf16_t)v1.w;
    *(bf16x8*)(A + (size_t)t * 8) = o;
  } else {
    // W2T[i][v][h] = bf16(W2[i][h][v]); one 16B chunk (8 h) per thread
    int t = (bx - 9216) * 256 + tid; // 0..64K-1
    int i = t >> 11;                 // 2048 chunks per i
    int rem = t & 2047;
    int h8 = rem >> 6;               // 0..31
    int v = rem & 63;                // consecutive lanes -> consecutive v
    const float* src = W2 + ((size_t)(i * 256 + h8 * 8)) * 64 + v;
    bf16x8 o;
#pragma unroll
    for (int r = 0; r < 8; ++r) o[r] = (bf16_t)src[(size_t)r * 64];
    *(bf16x8*)(W2T + ((size_t)(i * 64 + v)) * 256 + h8 * 8) = o;
  }
}

// ---------------- fused: GEMM1 (128x256xK2048) + gelu -> LDS -> GEMM2 (x64) + LN ----------------
__global__ __launch_bounds__(512, 2) void sem_main_kernel(
    const bf16_t* __restrict__ A, const bf16_t* __restrict__ W1T,
    const bf16_t* __restrict__ W2T,
    const float* __restrict__ b1, const float* __restrict__ b2,
    const float* __restrict__ gamma, const float* __restrict__ beta,
    float* __restrict__ out)
{
  __shared__ char smem[98304];   // GEMM1: Ab[2](16KB ea) + Bb[2](32KB ea); GEMM2: Hs 128x264 bf16

  // XCD swizzle: 8 consecutive logical blocks (same i) land on one XCD
  int p = blockIdx.x;
  int L = (p & 7) * 32 + (p >> 3);
  int i = L >> 3;       // group 0..31
  int mb = L & 7;       // M-block 0..7
  int brow = mb * 128;

  int tid = threadIdx.x;
  int lane = tid & 63;
  int wid = tid >> 6;     // 0..7
  int wr = wid >> 2;      // 0..1  (row 64-block)
  int wc = wid & 3;       // 0..3  (col 64-block)
  int lhi = lane >> 4;    // 0..3
  int llo = lane & 15;

  f32x4 acc[4][4];
#pragma unroll
  for (int m = 0; m < 4; ++m)
#pragma unroll
    for (int n = 0; n < 4; ++n) acc[m][n] = (f32x4){0.f, 0.f, 0.f, 0.f};

  const bf16_t* W1Ti = W1T + (size_t)i * 256 * 2048;

  // stage tile kt into buffer b: LDS linear dest, inverse-XOR-swizzled global source (G21)
  auto stage = [&](int b, int kt) {
    char* Ad = smem + b * 16384;
    char* Bd = smem + 32768 + b * 32768;
    // A tile: [128 rows][64 k] bf16 = 16KB, 2 rounds
#pragma unroll
    for (int it = 0; it < 2; ++it) {
      int s = (tid + it * 512) * 16;      // byte slot in tile
      int row = s >> 7;                   // 128B per row
      int chunk = (s & 127) >> 4;
      int sc = chunk ^ (row & 7);
      const bf16_t* g = A + (size_t)(brow + row) * 2048 + kt * 64 + sc * 8;
      GLD16(g, Ad + it * 8192 + wid * 1024);
    }
    // B tile: [256 h][64 k] bf16 = 32KB, 4 rounds
#pragma unroll
    for (int it = 0; it < 4; ++it) {
      int s = (tid + it * 512) * 16;
      int hrow = s >> 7;
      int chunk = (s & 127) >> 4;
      int sc = chunk ^ (hrow & 7);
      const bf16_t* g = W1Ti + (size_t)hrow * 2048 + kt * 64 + sc * 8;
      GLD16(g, Bd + it * 8192 + wid * 1024);
    }
  };

  stage(0, 0);
  for (int kt = 0; kt < 32; ++kt) {
    __syncthreads();                       // staged data for kt visible (vmcnt drained)
    if (kt + 1 < 32) stage((kt + 1) & 1, kt + 1);
    const char* At = smem + (kt & 1) * 16384;
    const char* Bt = smem + 32768 + (kt & 1) * 32768;
#pragma unroll
    for (int kk = 0; kk < 2; ++kk) {
      bf16x8 af[4], bfr[4];
#pragma unroll
      for (int m = 0; m < 4; ++m) {
        int row = wr * 64 + m * 16 + llo;
        int sc = (kk * 4 + lhi) ^ (row & 7);
        af[m] = *(const bf16x8*)(At + row * 128 + sc * 16);
      }
#pragma unroll
      for (int n = 0; n < 4; ++n) {
        int hrow = wc * 64 + n * 16 + llo;
        int sc = (kk * 4 + lhi) ^ (hrow & 7);
        bfr[n] = *(const bf16x8*)(Bt + hrow * 128 + sc * 16);
      }
#pragma unroll
      for (int m = 0; m < 4; ++m)
#pragma unroll
        for (int n = 0; n < 4; ++n)
          acc[m][n] = __builtin_amdgcn_mfma_f32_16x16x32_bf16(af[m], bfr[n], acc[m][n], 0, 0, 0);
    }
    __syncthreads();                       // all reads of this buffer done before restage
  }

  // ---- epilogue 1: bias + exact gelu -> Hs (bf16, stride 264 elems) ----
  bf16_t* Hs = (bf16_t*)smem;              // [128][264]
  float bias[4];
#pragma unroll
  for (int n = 0; n < 4; ++n) bias[n] = b1[i * 256 + wc * 64 + n * 16 + llo];
#pragma unroll
  for (int m = 0; m < 4; ++m) {
#pragma unroll
    for (int n = 0; n < 4; ++n) {
      int col = wc * 64 + n * 16 + llo;
#pragma unroll
      for (int r = 0; r < 4; ++r) {
        int row = wr * 64 + m * 16 + lhi * 4 + r;   // D layout: row=(lane>>4)*4+reg, col=lane&15
        float x = acc[m][n][r] + bias[n];
        float gl = 0.5f * x * (1.0f + erff(x * 0.70710678118654752f));
        Hs[row * 264 + col] = (bf16_t)gl;
      }
    }
  }
  __syncthreads();

  // ---- GEMM2: Y(128x64) = Hs(128x256) @ W2T_i^T, per wave 16 rows ----
  f32x4 acc2[4];
#pragma unroll
  for (int n = 0; n < 4; ++n) acc2[n] = (f32x4){0.f, 0.f, 0.f, 0.f};
  const bf16_t* W2Ti = W2T + (size_t)i * 64 * 256;
#pragma unroll
  for (int kk = 0; kk < 8; ++kk) {
    int k = kk * 32 + lhi * 8;
    bf16x8 af = *(const bf16x8*)(Hs + (wid * 16 + llo) * 264 + k);
#pragma unroll
    for (int n = 0; n < 4; ++n) {
      bf16x8 bfr = *(const bf16x8*)(W2Ti + (size_t)(n * 16 + llo) * 256 + k);
      acc2[n] = __builtin_amdgcn_mfma_f32_16x16x32_bf16(af, bfr, acc2[n], 0, 0, 0);
    }
  }

  // ---- epilogue 2: bias + LayerNorm(v=64) + affine -> out ----
  float b2v[4], gam[4], bet[4];
#pragma unroll
  for (int n = 0; n < 4; ++n) {
    int v = n * 16 + llo;
    b2v[n] = b2[i * 64 + v];
    gam[n] = gamma[i * 64 + v];
    bet[n] = beta[i * 64 + v];
  }
#pragma unroll
  for (int r = 0; r < 4; ++r) {
    float yv[4], s = 0.f, sq = 0.f;
#pragma unroll
    for (int n = 0; n < 4; ++n) {
      yv[n] = acc2[n][r] + b2v[n];
      s += yv[n];
      sq += yv[n] * yv[n];
    }
#pragma unroll
    for (int off = 1; off < 16; off <<= 1) {
      s += __shfl_xor(s, off, 64);
      sq += __shfl_xor(sq, off, 64);
    }
    float mu = s * (1.0f / 64.0f);
    float var = sq * (1.0f / 64.0f) - mu * mu;
    float rstd = rsqrtf(var + 1e-5f);
    int row = brow + wid * 16 + lhi * 4 + r;
    float* op = out + ((size_t)row * 32 + i) * 64;
#pragma unroll
    for (int n = 0; n < 4; ++n)
      op[n * 16 + llo] = (yv[n] - mu) * rstd * gam[n] + bet[n];
  }
}

extern "C" void kernel_launch(void* const* d_in, const int* in_sizes, int n_in,
                              void* d_out, int out_size, void* d_ws, size_t ws_size,
                              hipStream_t stream) {
  const float* cv    = (const float*)d_in[0];
  const float* adj   = (const float*)d_in[1];
  const float* W1    = (const float*)d_in[2];
  const float* b1    = (const float*)d_in[3];
  const float* W2    = (const float*)d_in[4];
  const float* b2    = (const float*)d_in[5];
  const float* gamma = (const float*)d_in[6];
  const float* beta  = (const float*)d_in[7];
  float* out = (float*)d_out;

  bf16_t* Abf  = (bf16_t*)((char*)d_ws + OFF_A);
  bf16_t* W1T  = (bf16_t*)((char*)d_ws + OFF_W1T);
  bf16_t* W2T  = (bf16_t*)((char*)d_ws + OFF_W2T);

  prep_kernel<<<9472, 256, 0, stream>>>(cv, adj, W1, W2, Abf, W1T, W2T);
  sem_main_kernel<<<256, 512, 0, stream>>>(Abf, W1T, W2T, b1, b2, gamma, beta, out);
}

// Round 3
// 68.815 us; speedup vs baseline: 1.2502x; 1.2502x over previous
//
#include <hip/hip_runtime.h>
#include <hip/hip_bf16.h>

typedef __bf16 bf16_t;
typedef __bf16 bf16x8 __attribute__((ext_vector_type(8)));
typedef float f32x4 __attribute__((ext_vector_type(4)));

#define NB 1024
#define ND 32
#define VD 64
#define NH 256
#define NK 2048

// workspace layout (bytes)
#define OFF_A    0                       // 1024*2048 bf16 = 4 MB
#define OFF_W1T  (4u*1024u*1024u)        // 32*256*2048 bf16 = 32 MB
#define OFF_W2T  (36u*1024u*1024u)       // 32*64*256 bf16 = 1 MB

#define GLD16(gsrc, ldst) \
  __builtin_amdgcn_global_load_lds((const __attribute__((address_space(1))) void*)(gsrc), \
                                   (__attribute__((address_space(3))) void*)(ldst), 16, 0, 0)

// ---------------- prep ----------------
// bx [0,4096):   W1T[i][h][k] = bf16(adj[i][k/64]*W1[i][k][h]) via LDS 64x64 transpose
// bx [4096,5120): A cast
// bx [5120,5376): W2T transpose (small)
__global__ __launch_bounds__(256) void prep_kernel(
    const float* __restrict__ cv, const float* __restrict__ adj,
    const float* __restrict__ W1, const float* __restrict__ W2,
    bf16_t* __restrict__ A, bf16_t* __restrict__ W1T, bf16_t* __restrict__ W2T)
{
  __shared__ float Ls[64 * 67];
  int bx = blockIdx.x;
  int tid = threadIdx.x;
  if (bx < 4096) {
    int i = bx >> 7;
    int rem = bx & 127;
    int k0 = (rem >> 2) * 64;
    int h0 = (rem & 3) * 64;
    float a = adj[i * 32 + (k0 >> 6)];       // one parent j per 64-k tile
    // read W1[i][k0+row][h0..h0+63], scaled, into Ls[row][col]
    int rrow = tid >> 4, c4 = (tid & 15) * 4;
#pragma unroll
    for (int p = 0; p < 4; ++p) {
      int row = p * 16 + rrow;
      const float* src = W1 + ((size_t)(i * 2048 + k0 + row)) * 256 + h0 + c4;
      float4 v = *(const float4*)src;
#pragma unroll
      for (int j = 0; j < 4; ++j) Ls[row * 67 + c4 + j] = a * ((const float*)&v)[j];
    }
    __syncthreads();
    // write W1T[i][h0+h][k0 + c8*8 .. +7]
#pragma unroll
    for (int p = 0; p < 2; ++p) {
      int u = p * 256 + tid;
      int h = u >> 3, c8 = u & 7;
      bf16x8 o;
#pragma unroll
      for (int j = 0; j < 8; ++j) o[j] = (bf16_t)Ls[(c8 * 8 + j) * 67 + h];
      *(bf16x8*)(W1T + ((size_t)(i * 256 + h0 + h)) * 2048 + k0 + c8 * 8) = o;
    }
  } else if (bx < 5120) {
    int t = (bx - 4096) * 256 + tid;
    const float4* s = (const float4*)cv + (size_t)t * 2;
    float4 v0 = s[0], v1 = s[1];
    bf16x8 o;
    o[0] = (bf16_t)v0.x; o[1] = (bf16_t)v0.y; o[2] = (bf16_t)v0.z; o[3] = (bf16_t)v0.w;
    o[4] = (bf16_t)v1.x; o[5] = (bf16_t)v1.y; o[6] = (bf16_t)v1.z; o[7] = (bf16_t)v1.w;
    *(bf16x8*)(A + (size_t)t * 8) = o;
  } else {
    int t = (bx - 5120) * 256 + tid;   // 0..64K-1
    int i = t >> 11;
    int rem = t & 2047;
    int h8 = rem >> 6;
    int v = rem & 63;
    const float* src = W2 + ((size_t)(i * 256 + h8 * 8)) * 64 + v;
    bf16x8 o;
#pragma unroll
    for (int r = 0; r < 8; ++r) o[r] = (bf16_t)src[(size_t)r * 64];
    *(bf16x8*)(W2T + ((size_t)(i * 64 + v)) * 256 + h8 * 8) = o;
  }
}

// ---------------- fused main: GEMM1 (128x256, BK=32, 4-deep pipeline) + gelu -> GEMM2 + LN ----
__global__ __launch_bounds__(512, 2) void sem_main_kernel(
    const bf16_t* __restrict__ A, const bf16_t* __restrict__ W1T,
    const bf16_t* __restrict__ W2T,
    const float* __restrict__ b1, const float* __restrict__ b2,
    const float* __restrict__ gamma, const float* __restrict__ beta,
    float* __restrict__ out)
{
  __shared__ char smem[98304];   // 4 x (A 8KB + B 16KB) = 96KB; epilogue: Hs 128x264 bf16

  // XCD swizzle: blocks on one XCD share 4 groups' B panels (4MB = L2)
  int p = blockIdx.x;
  int L = (p & 7) * 32 + (p >> 3);
  int i = L >> 3;       // group 0..31
  int brow = (L & 7) * 128;

  int tid = threadIdx.x;
  int lane = tid & 63;
  int wid = tid >> 6;     // 0..7
  int wr = wid >> 2;      // 0..1
  int wc = wid & 3;       // 0..3
  int lhi = lane >> 4;    // 0..3
  int llo = lane & 15;

  f32x4 acc[4][4];
#pragma unroll
  for (int m = 0; m < 4; ++m)
#pragma unroll
    for (int n = 0; n < 4; ++n) acc[m][n] = (f32x4){0.f, 0.f, 0.f, 0.f};

  const bf16_t* W1Ti = W1T + (size_t)i * 256 * 2048;

  // stage tile kt (BK=32) into buffer b: 3 gload_lds/thread; source pre-swizzled (G21)
  auto stage = [&](int b, int kt) {
    char* Ad = smem + b * 24576;
    char* Bd = Ad + 8192;
    {
      int row = tid >> 2, c = tid & 3;
      int sc = c ^ ((row >> 1) & 3);
      const bf16_t* g = A + (size_t)(brow + row) * 2048 + kt * 32 + sc * 8;
      GLD16(g, Ad + wid * 1024);
    }
#pragma unroll
    for (int it = 0; it < 2; ++it) {
      int s = tid + it * 512;
      int row = s >> 2, c = s & 3;
      int sc = c ^ ((row >> 1) & 3);
      const bf16_t* g = W1Ti + (size_t)row * 2048 + kt * 32 + sc * 8;
      GLD16(g, Bd + it * 8192 + wid * 1024);
    }
  };

  auto compute = [&](int t) {
    const char* At = smem + (t & 3) * 24576;
    const char* Bt = At + 8192;
    bf16x8 af[4], bfr[4];
#pragma unroll
    for (int m = 0; m < 4; ++m) {
      int row = wr * 64 + m * 16 + llo;
      int sc = lhi ^ ((row >> 1) & 3);
      af[m] = *(const bf16x8*)(At + row * 64 + sc * 16);
    }
#pragma unroll
    for (int n = 0; n < 4; ++n) {
      int hrow = wc * 64 + n * 16 + llo;
      int sc = lhi ^ ((hrow >> 1) & 3);
      bfr[n] = *(const bf16x8*)(Bt + hrow * 64 + sc * 16);
    }
    __builtin_amdgcn_s_setprio(1);
#pragma unroll
    for (int m = 0; m < 4; ++m)
#pragma unroll
      for (int n = 0; n < 4; ++n)
        acc[m][n] = __builtin_amdgcn_mfma_f32_16x16x32_bf16(af[m], bfr[n], acc[m][n], 0, 0, 0);
    __builtin_amdgcn_s_setprio(0);
  };

  asm volatile("" ::: "memory");     // keep epilogue loads below; pin prologue
  stage(0, 0); stage(1, 1); stage(2, 2);

  for (int t = 0; t < 61; ++t) {
    asm volatile("s_waitcnt vmcnt(6)" ::: "memory");   // own tile-t loads done
    __builtin_amdgcn_s_barrier();                      // => ALL waves' tile-t loads done
    asm volatile("" ::: "memory");
    stage((t + 3) & 3, t + 3);                         // overwrites buf (t-1)&3 (reads done)
    compute(t);
  }
  asm volatile("s_waitcnt vmcnt(6)" ::: "memory");
  __builtin_amdgcn_s_barrier();
  asm volatile("" ::: "memory");
  compute(61);
  asm volatile("s_waitcnt vmcnt(3)" ::: "memory");
  __builtin_amdgcn_s_barrier();
  asm volatile("" ::: "memory");
  compute(62);
  asm volatile("s_waitcnt vmcnt(0)" ::: "memory");
  __builtin_amdgcn_s_barrier();
  asm volatile("" ::: "memory");
  compute(63);

  __syncthreads();   // full drain before smem reuse

  // ---- epilogue 1: bias + exact gelu -> Hs (bf16, stride 264) ----
  bf16_t* Hs = (bf16_t*)smem;              // [128][264]
  float bias[4];
#pragma unroll
  for (int n = 0; n < 4; ++n) bias[n] = b1[i * 256 + wc * 64 + n * 16 + llo];
#pragma unroll
  for (int m = 0; m < 4; ++m) {
#pragma unroll
    for (int n = 0; n < 4; ++n) {
      int col = wc * 64 + n * 16 + llo;
#pragma unroll
      for (int r = 0; r < 4; ++r) {
        int row = wr * 64 + m * 16 + lhi * 4 + r;   // D: row=(lane>>4)*4+reg, col=lane&15
        float x = acc[m][n][r] + bias[n];
        float gl = 0.5f * x * (1.0f + erff(x * 0.70710678118654752f));
        Hs[row * 264 + col] = (bf16_t)gl;
      }
    }
  }
  __syncthreads();

  // ---- GEMM2: Y(128x64) = Hs(128x256) @ W2T_i^T ----
  f32x4 acc2[4];
#pragma unroll
  for (int n = 0; n < 4; ++n) acc2[n] = (f32x4){0.f, 0.f, 0.f, 0.f};
  const bf16_t* W2Ti = W2T + (size_t)i * 64 * 256;
#pragma unroll
  for (int kk = 0; kk < 8; ++kk) {
    int k = kk * 32 + lhi * 8;
    bf16x8 af = *(const bf16x8*)(Hs + (wid * 16 + llo) * 264 + k);
#pragma unroll
    for (int n = 0; n < 4; ++n) {
      bf16x8 bfr = *(const bf16x8*)(W2Ti + (size_t)(n * 16 + llo) * 256 + k);
      acc2[n] = __builtin_amdgcn_mfma_f32_16x16x32_bf16(af, bfr, acc2[n], 0, 0, 0);
    }
  }

  // ---- epilogue 2: bias + LayerNorm(v=64) + affine -> out ----
  float b2v[4], gam[4], bet[4];
#pragma unroll
  for (int n = 0; n < 4; ++n) {
    int v = n * 16 + llo;
    b2v[n] = b2[i * 64 + v];
    gam[n] = gamma[i * 64 + v];
    bet[n] = beta[i * 64 + v];
  }
#pragma unroll
  for (int r = 0; r < 4; ++r) {
    float yv[4], s = 0.f, sq = 0.f;
#pragma unroll
    for (int n = 0; n < 4; ++n) {
      yv[n] = acc2[n][r] + b2v[n];
      s += yv[n];
      sq += yv[n] * yv[n];
    }
#pragma unroll
    for (int off = 1; off < 16; off <<= 1) {
      s += __shfl_xor(s, off, 64);
      sq += __shfl_xor(sq, off, 64);
    }
    float mu = s * (1.0f / 64.0f);
    float var = sq * (1.0f / 64.0f) - mu * mu;
    float rstd = rsqrtf(var + 1e-5f);
    int row = brow + wid * 16 + lhi * 4 + r;
    float* op = out + ((size_t)row * 32 + i) * 64;
#pragma unroll
    for (int n = 0; n < 4; ++n)
      op[n * 16 + llo] = (yv[n] - mu) * rstd * gam[n] + bet[n];
  }
}

extern "C" void kernel_launch(void* const* d_in, const int* in_sizes, int n_in,
                              void* d_out, int out_size, void* d_ws, size_t ws_size,
                              hipStream_t stream) {
  const float* cv    = (const float*)d_in[0];
  const float* adj   = (const float*)d_in[1];
  const float* W1    = (const float*)d_in[2];
  const float* b1    = (const float*)d_in[3];
  const float* W2    = (const float*)d_in[4];
  const float* b2    = (const float*)d_in[5];
  const float* gamma = (const float*)d_in[6];
  const float* beta  = (const float*)d_in[7];
  float* out = (float*)d_out;

  bf16_t* Abf  = (bf16_t*)((char*)d_ws + OFF_A);
  bf16_t* W1T  = (bf16_t*)((char*)d_ws + OFF_W1T);
  bf16_t* W2T  = (bf16_t*)((char*)d_ws + OFF_W2T);

  prep_kernel<<<5376, 256, 0, stream>>>(cv, adj, W1, W2, Abf, W1T, W2T);
  sem_main_kernel<<<256, 512, 0, stream>>>(Abf, W1T, W2T, b1, b2, gamma, beta, out);
}